// Round 14
// baseline (1137.478 us; speedup 1.0000x reference)
//
#include <hip/hip_runtime.h>

typedef _Float16 f16;
typedef _Float16 half8 __attribute__((ext_vector_type(8)));
typedef float f32x4 __attribute__((ext_vector_type(4)));

#define TOK 49
#define HEADS 8

// XOR swizzle: spreads rows across LDS banks
__device__ __forceinline__ int swzX(int row, int kb) { return row * 1024 + (kb ^ ((row & 7) << 4)); }
__device__ __forceinline__ int swz64(int row, int cb) { return row * 128 + (cb ^ ((row & 7) << 4)); }

// ws layout (f16 elems): wf[16 kc][96 ntile][64 lane][8] fragment-ordered weights (1.5MB)
// ntile n-cols: Q = ntiles 0..31, K = 32..63, V = 64..95; head h = 4 ntiles.
__global__ void prep_wfrag(const float* __restrict__ wq,
                           const float* __restrict__ wk,
                           const float* __restrict__ wv,
                           f16* __restrict__ wf) {
    int gid = blockIdx.x * 256 + threadIdx.x;   // 0 .. 98303
    int kc   = gid / 6144;
    int rem  = gid % 6144;
    int nt   = rem >> 6;
    int lane = rem & 63;
    int n    = nt * 16 + (lane & 15);
    int m    = n >> 9;
    int nloc = n & 511;
    int k0   = kc * 32 + (lane >> 4) * 8;
    const float* w = (m == 0) ? wq : (m == 1) ? wk : wv;
    half8 h;
    #pragma unroll
    for (int e = 0; e < 8; ++e) h[e] = (f16)w[(size_t)(k0 + e) * 512 + nloc];
    *(half8*)(wf + (size_t)gid * 8) = h;
}

// ======================= FUSED GEMM + ATTENTION =============================
// One block = one window (512 thr / 8 waves). TWO head-groups of 4 heads:
// per group, R8's proven barrier-free QKV k-loop (6 ntiles/wave, acc[6][4],
// B coalesced direct from L2, A from swizzled Xs) -> stage 12 head-tiles
// (96KB; Q/K row-major swz64, V transposed) -> barrier -> attention with
// 2 waves per head (wave = head_local*2 + row_half; halves own disjoint
// mt row-pairs; P overwrites own Q-tile rows, wave-coherent). 5 barriers
// per window. LDS = 50KB Xs + 96KB Stg = 146KB. Kills the 0.4GB qkv write
// + 0.6GB attn re-read + attn dispatch of the split design.
__global__ __launch_bounds__(512, 1)
void swin_fused(const float* __restrict__ x,
                const float* __restrict__ bqv,
                const float* __restrict__ bkv,
                const float* __restrict__ bvv,
                const float* __restrict__ pos_bias,
                const f16* __restrict__ wf,
                float* __restrict__ out) {
    __shared__ f16 Xs [50 * 512];      // 50KB swizzled; row 49 zero
    __shared__ f16 Stg[12 * 4096];     // 96KB: 12 head-tiles (Q4,K4,V4)

    const int win  = blockIdx.x;
    const int bb   = win >> 6;
    const int wy   = (win >> 3) & 7;
    const int wx   = win & 7;
    const int tid  = threadIdx.x;
    const int wave = tid >> 6;        // 0..7
    const int lane = tid & 63;
    const int l15  = lane & 15;
    const int lg   = lane >> 4;

    // ---- stage X window -> LDS f16 (swizzled); row 49 zeroed ----
    #pragma unroll
    for (int it = 0; it < 7; ++it) {
        int idx = it * 512 + tid;                 // vec8 slots, 3200 total
        if (idx < 3200) {
            int elem = idx * 8;
            int m = elem >> 9;
            int k = elem & 511;
            half8 h = {(f16)0, (f16)0, (f16)0, (f16)0, (f16)0, (f16)0, (f16)0, (f16)0};
            if (m < TOK) {
                int i = m / 7, j = m - i * 7;
                const float* src = x + (((size_t)(bb * 56 + wy * 7 + i)) * 56 + (wx * 7 + j)) * 512 + k;
                float4 f0 = ((const float4*)src)[0];
                float4 f1 = ((const float4*)src)[1];
                h[0] = (f16)f0.x; h[1] = (f16)f0.y; h[2] = (f16)f0.z; h[3] = (f16)f0.w;
                h[4] = (f16)f1.x; h[5] = (f16)f1.y; h[6] = (f16)f1.z; h[7] = (f16)f1.w;
            }
            *(half8*)((char*)Xs + swzX(m, k * 2)) = h;
        }
    }
    __syncthreads();                              // barrier: Xs ready

    int rowA[4];
    #pragma unroll
    for (int mt = 0; mt < 4; ++mt) {
        int rr = mt * 16 + l15;
        rowA[mt] = (rr < TOK) ? rr : TOK;         // clamp pad rows to zero row 49
    }

    const float scale = 0.044194173824159216f;    // 1/sqrt(512)

    for (int g = 0; g < 2; ++g) {                 // head group: heads 4g..4g+3
        // ---------------- Phase 1: QKV projection for this group ----------------
        // wave owns local ntiles ln = 6*wave .. 6*wave+5 of the group's 48:
        // ln -> m = ln>>4 (0=Q 1=K 2=V), t = ln&15; global ntile = m*32 + g*16 + t
        int boff[6];                              // wf element offset per j (kc=0)
        #pragma unroll
        for (int j = 0; j < 6; ++j) {
            int ln  = 6 * wave + j;
            int ntg = ((ln >> 4) << 5) + g * 16 + (ln & 15);
            boff[j] = ntg * 512 + lane * 8;
        }

        f32x4 acc[6][4];
        #pragma unroll
        for (int j = 0; j < 6; ++j)
            #pragma unroll
            for (int mt = 0; mt < 4; ++mt)
                acc[j][mt] = {0.f, 0.f, 0.f, 0.f};

        for (int kc = 0; kc < 16; ++kc) {
            const f16* wk0 = wf + (size_t)kc * 49152;   // 96 ntiles * 512
            half8 b[6];
            #pragma unroll
            for (int j = 0; j < 6; ++j)
                b[j] = *(const half8*)(wk0 + boff[j]);  // coalesced 1KB/wave
            half8 a[4];
            #pragma unroll
            for (int mt = 0; mt < 4; ++mt)
                a[mt] = *(const half8*)((char*)Xs + swzX(rowA[mt], kc * 64 + lg * 16));
            #pragma unroll
            for (int j = 0; j < 6; ++j)
                #pragma unroll
                for (int mt = 0; mt < 4; ++mt)
                    acc[j][mt] = __builtin_amdgcn_mfma_f32_16x16x32_f16(a[mt], b[j], acc[j][mt], 0, 0, 0);
        }

        // epilogue: stage 12 tiles. slot = m*4 + head_local; Q/K row-major
        // swz64; V transposed [ch][tok] (tokens>=49 get bias -> finite, P=0 kills).
        #pragma unroll
        for (int j = 0; j < 6; ++j) {
            const int ln  = 6 * wave + j;
            const int m   = ln >> 4;                  // 0=Q 1=K 2=V
            const int t   = ln & 15;
            const int sl  = m * 4 + (t >> 2);         // tile slot 0..11
            const int ch  = (t & 3) * 16 + l15;       // in-tile channel 0..63
            const float* bias = (m == 0) ? bqv : (m == 1) ? bkv : bvv;
            const float bs = bias[g * 256 + t * 16 + l15];
            char* tile = (char*)Stg + sl * 8192;
            if (m < 2) {
                #pragma unroll
                for (int mt = 0; mt < 4; ++mt) {
                    const int t0 = mt * 16 + lg * 4;
                    #pragma unroll
                    for (int r = 0; r < 4; ++r)
                        *(f16*)(tile + swz64(t0 + r, ch * 2)) = (f16)(acc[j][mt][r] + bs);
                }
            } else {
                #pragma unroll
                for (int mt = 0; mt < 4; ++mt) {
                    const int t0 = mt * 16 + lg * 4;
                    half8 vv;
                    #pragma unroll
                    for (int r = 0; r < 4; ++r) vv[r] = (f16)(acc[j][mt][r] + bs);
                    *(uint2*)(tile + swz64(ch, t0 * 2)) = *(const uint2*)&vv;  // transposed
                }
            }
        }
        __syncthreads();                              // tiles ready

        // ---------------- Phase 2: attention, 2 waves per head ----------------
        {
            const int hl   = wave >> 1;               // head_local 0..3
            const int half = wave & 1;                // row half: mt in {2*half, 2*half+1}
            const int head = g * 4 + hl;
            char* tQ = (char*)Stg + hl * 8192;        // P reuses own rows of this slot
            char* tK = (char*)Stg + (4 + hl) * 8192;
            char* tV = (char*)Stg + (8 + hl) * 8192;
            const float* pb = pos_bias + head * TOK * TOK;

            // hoist this half's Q A-frags before P overwrites those rows
            half8 qa[2][2];
            #pragma unroll
            for (int mi = 0; mi < 2; ++mi) {
                const int mt = 2 * half + mi;
                #pragma unroll
                for (int ks = 0; ks < 2; ++ks)
                    qa[mi][ks] = *(const half8*)(tQ + swz64(mt * 16 + l15, (ks * 32 + lg * 8) * 2));
            }

            #pragma unroll
            for (int mi = 0; mi < 2; ++mi) {
                const int mt = 2 * half + mi;
                f32x4 sacc[4];
                #pragma unroll
                for (int nt = 0; nt < 4; ++nt) sacc[nt] = {0.f, 0.f, 0.f, 0.f};
                #pragma unroll
                for (int nt = 0; nt < 4; ++nt)
                    #pragma unroll
                    for (int ks = 0; ks < 2; ++ks) {
                        half8 kb = *(const half8*)(tK + swz64(nt * 16 + l15, (ks * 32 + lg * 8) * 2));
                        sacc[nt] = __builtin_amdgcn_mfma_f32_16x16x32_f16(qa[mi][ks], kb, sacc[nt], 0, 0, 0);
                    }
                #pragma unroll
                for (int r = 0; r < 4; ++r) {
                    const int q  = mt * 16 + lg * 4 + r;
                    const int qp = (q < TOK) ? q : 0;
                    float sv[4];
                    float rmax = -3.4028235e38f;
                    #pragma unroll
                    for (int nt = 0; nt < 4; ++nt) {
                        const int t2 = nt * 16 + l15;
                        const int tp = (t2 < TOK) ? t2 : 0;
                        float s = sacc[nt][r] * scale + pb[qp * TOK + tp];
                        const bool valid = (q < TOK) && (t2 < TOK) && (t2 != q);
                        s = valid ? s : -3.4028235e38f;   // eye-mask = finfo.min
                        sv[nt] = s;
                        rmax = fmaxf(rmax, s);
                    }
                    #pragma unroll
                    for (int md = 1; md < 16; md <<= 1)
                        rmax = fmaxf(rmax, __shfl_xor(rmax, md));
                    float rsum = 0.f;
                    #pragma unroll
                    for (int nt = 0; nt < 4; ++nt) {
                        float e = __expf(sv[nt] - rmax);
                        sv[nt] = e;
                        rsum += e;
                    }
                    #pragma unroll
                    for (int md = 1; md < 16; md <<= 1)
                        rsum += __shfl_xor(rsum, md);
                    const float inv = 1.f / rsum;
                    #pragma unroll
                    for (int nt = 0; nt < 4; ++nt)
                        *(f16*)(tQ + swz64(q, (nt * 16 + l15) * 2)) = (f16)(sv[nt] * inv);
                }
            }

            // O = P V for this half's rows (P rows written by this wave)
            #pragma unroll
            for (int mi = 0; mi < 2; ++mi) {
                const int mt = 2 * half + mi;
                half8 pa[2];
                #pragma unroll
                for (int ks = 0; ks < 2; ++ks)
                    pa[ks] = *(const half8*)(tQ + swz64(mt * 16 + l15, (ks * 32 + lg * 8) * 2));
                f32x4 oacc[4];
                #pragma unroll
                for (int ct = 0; ct < 4; ++ct) oacc[ct] = {0.f, 0.f, 0.f, 0.f};
                #pragma unroll
                for (int ct = 0; ct < 4; ++ct)
                    #pragma unroll
                    for (int ks = 0; ks < 2; ++ks) {
                        half8 vb = *(const half8*)(tV + swz64(ct * 16 + l15, (ks * 32 + lg * 8) * 2));
                        oacc[ct] = __builtin_amdgcn_mfma_f32_16x16x32_f16(pa[ks], vb, oacc[ct], 0, 0, 0);
                    }
                #pragma unroll
                for (int r = 0; r < 4; ++r) {
                    const int q = mt * 16 + lg * 4 + r;
                    if (q < TOK) {
                        #pragma unroll
                        for (int ct = 0; ct < 4; ++ct)
                            out[((size_t)win * TOK + q) * 512 + head * 64 + ct * 16 + l15] = oacc[ct][r];
                    }
                }
            }
        }
        __syncthreads();   // group done: Stg (incl. P slots) safe to overwrite
    }
}

extern "C" void kernel_launch(void* const* d_in, const int* in_sizes, int n_in,
                              void* d_out, int out_size, void* d_ws, size_t ws_size,
                              hipStream_t stream) {
    const float* x  = (const float*)d_in[0];
    const float* wq = (const float*)d_in[1];
    const float* bq = (const float*)d_in[2];
    const float* wk = (const float*)d_in[3];
    const float* bk = (const float*)d_in[4];
    const float* wv = (const float*)d_in[5];
    const float* bv = (const float*)d_in[6];
    const float* pb = (const float*)d_in[7];
    f16*   wf  = (f16*)d_ws;            // 1.5MB fragment-ordered weights
    float* out = (float*)d_out;

    prep_wfrag<<<384, 256, 0, stream>>>(wq, wk, wv, wf);
    swin_fused<<<2048, 512, 0, stream>>>(x, bq, bk, bv, pb, wf, out);
}